// Round 10
// baseline (184.433 us; speedup 1.0000x reference)
//
#include <hip/hip_runtime.h>

typedef unsigned short U16;
typedef __bf16 bf16x8 __attribute__((ext_vector_type(8)));
typedef float f32x4 __attribute__((ext_vector_type(4)));
typedef float f32x16 __attribute__((ext_vector_type(16)));

__device__ inline float b2f(U16 u) {
    union { unsigned int i; float f; } v;
    v.i = ((unsigned int)u) << 16;
    return v.f;
}
__device__ inline U16 f2b(float f) {
    union { float f; unsigned int u; } v;
    v.f = f;
    unsigned int r = (v.u + 0x7fffu + ((v.u >> 16) & 1u)) >> 16;
    return (U16)r;
}

// pack two f32 -> two bf16 in one u32 (RNE, same as f2b)
__device__ inline unsigned cvt_pk(float lo, float hi) {
    unsigned d;
    asm("v_cvt_pk_bf16_f32 %0, %1, %2" : "=v"(d) : "v"(lo), "v"(hi));
    return d;
}
// swap: a[lanes 32-63] <-> b[lanes 0-31]
__device__ inline void plswap(unsigned &a, unsigned &b) {
    asm("v_permlane32_swap_b32 %0, %1" : "+v"(a), "+v"(b));
}

// async global->LDS, 16B per lane (LDS dest = wave-uniform base + lane*16)
__device__ inline void gld16(const void* g, void* l) {
    __builtin_amdgcn_global_load_lds(
        (const __attribute__((address_space(1))) void*)g,
        (__attribute__((address_space(3))) void*)l, 16, 0, 0);
}

// ------- prep: LN (blocks 0..4095) + two weight transposes, ONE launch -----
__global__ __launch_bounds__(256) void prep_kernel(const float* __restrict__ x,
                                                   const float* __restrict__ gamma,
                                                   const float* __restrict__ beta,
                                                   U16* __restrict__ xn,
                                                   const float* __restrict__ Wqkv,
                                                   U16* __restrict__ WqT,
                                                   const float* __restrict__ Wout,
                                                   U16* __restrict__ WoT) {
    int p = blockIdx.x;
    int t = threadIdx.x;
    if (p < 4096) {
        // ---- LayerNorm row p: fp32 -> bf16 ----
        int row = p;
        float4 raw = ((const float4*)(x + (size_t)row * 1024))[t];
        float v[4] = { raw.x, raw.y, raw.z, raw.w };
        float s = v[0] + v[1] + v[2] + v[3];
        float s2 = v[0] * v[0] + v[1] * v[1] + v[2] * v[2] + v[3] * v[3];
#pragma unroll
        for (int off = 32; off >= 1; off >>= 1) {
            s  += __shfl_xor(s,  off);
            s2 += __shfl_xor(s2, off);
        }
        __shared__ float red[8];
        if ((t & 63) == 0) { red[(t >> 6) * 2] = s; red[(t >> 6) * 2 + 1] = s2; }
        __syncthreads();
        float S  = red[0] + red[2] + red[4] + red[6];
        float S2 = red[1] + red[3] + red[5] + red[7];
        float mu = S * (1.0f / 1024.0f);
        float var = S2 * (1.0f / 1024.0f) - mu * mu;
        float rstd = rsqrtf(var + 1e-5f);
        float4 g4 = ((const float4*)gamma)[t];
        float4 b4 = ((const float4*)beta)[t];
        ushort4 o;
        o.x = f2b((v[0] - mu) * rstd * g4.x + b4.x);
        o.y = f2b((v[1] - mu) * rstd * g4.y + b4.y);
        o.z = f2b((v[2] - mu) * rstd * g4.z + b4.z);
        o.w = f2b((v[3] - mu) * rstd * g4.w + b4.w);
        ((ushort4*)(xn + (size_t)row * 1024))[t] = o;
        return;
    }
    // ---- transpose + f2b: out[c][r] = bf16(in[r][c]) ----
    p -= 4096;
    const float* in; U16* out; int C, tilesx;
    if (p < 3072) { in = Wqkv; out = WqT; C = 3072; tilesx = 96; }
    else { p -= 3072; in = Wout; out = WoT; C = 1024; tilesx = 32; }
    const int R = 1024;
    int c0 = (p % tilesx) * 32, r0 = (p / tilesx) * 32;
    int tx = t & 31, ty = t >> 5;   // 32 x 8
    __shared__ float tile[32][33];
#pragma unroll
    for (int i = 0; i < 32; i += 8)
        tile[ty + i][tx] = in[(size_t)(r0 + ty + i) * C + c0 + tx];
    __syncthreads();
#pragma unroll
    for (int i = 0; i < 32; i += 8)
        out[(size_t)(c0 + ty + i) * R + r0 + tx] = f2b(tile[tx][ty + i]);
}

// ------ GEMM1: 256x192 tile, BK=64, 8 waves, counted-vmcnt pipeline.
// r9: full-chip grid (256 blocks) proven, total 181.0us. This round: ONE
// change — issue ALL of tile t+1's loads (A 4 + B 3) together at the TOP of
// tile t, wait vmcnt(7). Previously stB(t+1) was issued mid-tile (in P0), so
// at the next tile's wait those B-loads had only ~1/2 tile (~500cyc) of
// cover vs ~900cyc HBM latency — an exposed stall at 1 block/CU (no other
// block to hide it). Now every load gets a FULL tile (~1000+cyc) of cover.
// Ledger (per wave): entry 7 outstanding [tile t, issued at top of t-1];
// issue 7 -> 14; vmcnt(7) retires the 7 oldest = exactly tile t. Buf-reuse
// safe: the dest buffer was last read in tile t-1, behind its end-barrier.
// Prologue pays one ~900cyc stall; tail vmcnt(0) is fully covered.
__global__ __launch_bounds__(512) void gemm_g1(const U16* __restrict__ A,
                                               const U16* __restrict__ Bt,
                                               U16* __restrict__ C,
                                               U16* __restrict__ vT,
                                               int M, int N, int K) {
    __shared__ __align__(16) U16 As[2][2][128 * 64];   // 64 KB
    __shared__ __align__(16) U16 Bs[2][192 * 64];      // 48 KB
    const int p = blockIdx.x;
    const int xcd = p & 7, sl = p >> 3;              // sl in 0..31
    const int by = xcd * 2 + (sl >> 4);
    const int bx = sl & 15;
    const int m0 = by * 256, n0 = bx * 192;
    const int t = threadIdx.x;
    const int wave = t >> 6, lane = t & 63, l15 = lane & 15, quad = lane >> 4;
    const int wm = wave >> 2, wn = wave & 3;

    f32x4 acc[8][3];
#pragma unroll
    for (int i = 0; i < 8; i++)
#pragma unroll
        for (int j = 0; j < 3; j++)
            acc[i][j] = (f32x4){0.f, 0.f, 0.f, 0.f};

    // A staging: 2048 chunks per 256-row tile (2 halves x 1024), 4/thread
    const int c0 = t, c1 = 512 + t;
    const int sr0 = c0 >> 3, so0 = (c0 & 7) ^ (sr0 & 7);
    const int sr1 = c1 >> 3, so1 = (c1 & 7) ^ (sr1 & 7);
    const U16* Ag0 = A + (size_t)(m0 + sr0) * K + so0 * 8;
    const U16* Ag1 = A + (size_t)(m0 + sr1) * K + so1 * 8;
    const size_t hstep = (size_t)128 * K;           // +128 rows

    // B staging: 1536 chunks per 192-row tile, 3/thread
    const int cb2 = 1024 + t;
    const int sb2 = cb2 >> 3, ob2 = (cb2 & 7) ^ (sb2 & 7);
    const U16* Bg0 = Bt + (size_t)(n0 + sr0) * K + so0 * 8;   // chunk t
    const U16* Bg1 = Bt + (size_t)(n0 + sr1) * K + so1 * 8;   // chunk 512+t
    const U16* Bg2 = Bt + (size_t)(n0 + sb2) * K + ob2 * 8;   // chunk 1024+t

    auto stA = [&](int kt, U16* d0, U16* d1) {      // 4 loads
        gld16(Ag0 + kt * 64, d0 + c0 * 8);
        gld16(Ag1 + kt * 64, d0 + c1 * 8);
        gld16(Ag0 + hstep + kt * 64, d1 + c0 * 8);
        gld16(Ag1 + hstep + kt * 64, d1 + c1 * 8);
    };
    auto stB = [&](int kt, U16* d) {                // 3 loads
        gld16(Bg0 + kt * 64, d + c0 * 8);
        gld16(Bg1 + kt * 64, d + c1 * 8);
        gld16(Bg2 + kt * 64, d + cb2 * 8);
    };

    // frag-read offsets (elements): k 0..31 -> oct quad, k 32..63 -> 4+quad
    const int slot0 = quad ^ (l15 & 7);
    const int slot1 = (4 + quad) ^ (l15 & 7);
    const int aoff0 = l15 * 64 + slot0 * 8, aoff1 = l15 * 64 + slot1 * 8;
    const int boff0 = wn * 48 * 64 + aoff0, boff1 = wn * 48 * 64 + aoff1;
    const int nk = K >> 6;                          // 16

    auto ktile = [&](const U16* Ac0, const U16* Ac1, const U16* Bc,
                     U16* An0, U16* An1, U16* Bn, int kt) {
        const bool nx = (kt + 1) < nk;
        if (nx) {
            stA(kt + 1, An0, An1);
            stB(kt + 1, Bn);
            asm volatile("s_waitcnt vmcnt(7)" ::: "memory");
        } else {
            asm volatile("s_waitcnt vmcnt(0)" ::: "memory");
        }
        __builtin_amdgcn_s_barrier();
        asm volatile("" ::: "memory");
        const U16* Ah = wm ? Ac1 : Ac0;
        bf16x8 bfr[3][2], af[4][2];
#pragma unroll
        for (int j = 0; j < 3; j++) {
            bfr[j][0] = *(const bf16x8*)&Bc[j * 16 * 64 + boff0];
            bfr[j][1] = *(const bf16x8*)&Bc[j * 16 * 64 + boff1];
        }
#pragma unroll
        for (int i = 0; i < 4; i++) {
            af[i][0] = *(const bf16x8*)&Ah[i * 16 * 64 + aoff0];
            af[i][1] = *(const bf16x8*)&Ah[i * 16 * 64 + aoff1];
        }
        __builtin_amdgcn_s_setprio(1);
#pragma unroll
        for (int i = 0; i < 4; i++)
#pragma unroll
            for (int j = 0; j < 3; j++) {
                acc[i][j] = __builtin_amdgcn_mfma_f32_16x16x32_bf16(af[i][0], bfr[j][0], acc[i][j], 0, 0, 0);
                acc[i][j] = __builtin_amdgcn_mfma_f32_16x16x32_bf16(af[i][1], bfr[j][1], acc[i][j], 0, 0, 0);
            }
        __builtin_amdgcn_s_setprio(0);
        asm volatile("" ::: "memory");
        __builtin_amdgcn_s_barrier();
        asm volatile("" ::: "memory");
#pragma unroll
        for (int i = 0; i < 4; i++) {
            af[i][0] = *(const bf16x8*)&Ah[(4 + i) * 16 * 64 + aoff0];
            af[i][1] = *(const bf16x8*)&Ah[(4 + i) * 16 * 64 + aoff1];
        }
        __builtin_amdgcn_s_setprio(1);
#pragma unroll
        for (int i = 0; i < 4; i++)
#pragma unroll
            for (int j = 0; j < 3; j++) {
                acc[4 + i][j] = __builtin_amdgcn_mfma_f32_16x16x32_bf16(af[i][0], bfr[j][0], acc[4 + i][j], 0, 0, 0);
                acc[4 + i][j] = __builtin_amdgcn_mfma_f32_16x16x32_bf16(af[i][1], bfr[j][1], acc[4 + i][j], 0, 0, 0);
            }
        __builtin_amdgcn_s_setprio(0);
        asm volatile("" ::: "memory");
        __builtin_amdgcn_s_barrier();
        asm volatile("" ::: "memory");
    };

    // prologue: tile 0 -> buf 0 (7 loads in flight; first ktile waits them)
    stA(0, &As[0][0][0], &As[0][1][0]);
    stB(0, &Bs[0][0]);

    for (int kt = 0; kt < nk; kt += 2) {
        ktile(&As[0][0][0], &As[0][1][0], &Bs[0][0],
              &As[1][0][0], &As[1][1][0], &Bs[1][0], kt);
        ktile(&As[1][0][0], &As[1][1][0], &Bs[1][0],
              &As[0][0][0], &As[0][1][0], &Bs[0][0], kt + 1);
    }

    // epilogue: per-j V-vs-C branch (j-blocks are 16-aligned; 2048 % 16 == 0)
#pragma unroll
    for (int j = 0; j < 3; j++) {
        int cb = n0 + wn * 48 + j * 16;
        if (vT && cb >= 2048) {
#pragma unroll
            for (int i = 0; i < 8; i++) {
                int col = cb + l15 - 2048;
                int hh = col >> 6, dd = col & 63;
                int row0 = m0 + wm * 128 + i * 16 + quad * 4;
                int bb = row0 >> 11, nn = row0 & 2047;
                ushort4 st;
                st.x = f2b(acc[i][j][0]); st.y = f2b(acc[i][j][1]);
                st.z = f2b(acc[i][j][2]); st.w = f2b(acc[i][j][3]);
                *(ushort4*)&vT[((((size_t)bb * 16) + hh) * 64 + dd) * 2048 + nn] = st;
            }
        } else {
#pragma unroll
            for (int i = 0; i < 8; i++) {
                int col = cb + l15;
                int row0 = m0 + wm * 128 + i * 16 + quad * 4;
#pragma unroll
                for (int r = 0; r < 4; r++)
                    C[(size_t)(row0 + r) * N + col] = f2b(acc[i][j][r]);
            }
        }
    }
}

// ------ GEMM2: 64x128 tile, BK=64, counted-vmcnt pipeline. Same change as
// gemm_g1: all 6 loads of tile t+1 issued at the top of tile t, vmcnt(6)
// (entry 6 outstanding = tile t; +6 = 12; retire 6 oldest = tile t). Full-
// tile latency cover for B-loads (previously issued mid-tile).
__global__ __launch_bounds__(256) void gemm_bt2(const U16* __restrict__ A,
                                                const U16* __restrict__ Bt,
                                                const float* __restrict__ bias,
                                                float* __restrict__ C,
                                                int M, int N, int K) {
    __shared__ __align__(16) U16 As[2][64 * 64];
    __shared__ __align__(16) U16 Bs[2][128 * 64];
    const int m0 = blockIdx.y * 64, n0 = blockIdx.x * 128;
    const int t = threadIdx.x;
    const int wave = t >> 6, lane = t & 63, l15 = lane & 15, quad = lane >> 4;
    const int wm = (wave >> 1) * 32, wn = (wave & 1) * 64;

    f32x4 acc[2][4];
#pragma unroll
    for (int i = 0; i < 2; i++)
#pragma unroll
        for (int j = 0; j < 4; j++)
            acc[i][j] = (f32x4){0.f, 0.f, 0.f, 0.f};

    const int cA0 = t, cA1 = 256 + t;
    const int srA0 = cA0 >> 3, soA0 = (cA0 & 7) ^ (srA0 & 7);
    const int srA1 = cA1 >> 3, soA1 = (cA1 & 7) ^ (srA1 & 7);
    const U16* AgA0 = A + (size_t)(m0 + srA0) * K + soA0 * 8;
    const U16* AgA1 = A + (size_t)(m0 + srA1) * K + soA1 * 8;
    const int cB0 = t, cB1 = 256 + t, cB2 = 512 + t, cB3 = 768 + t;
    const int srB0 = cB0 >> 3, soB0 = (cB0 & 7) ^ (srB0 & 7);
    const int srB1 = cB1 >> 3, soB1 = (cB1 & 7) ^ (srB1 & 7);
    const int srB2 = cB2 >> 3, soB2 = (cB2 & 7) ^ (srB2 & 7);
    const int srB3 = cB3 >> 3, soB3 = (cB3 & 7) ^ (srB3 & 7);
    const U16* BgB0 = Bt + (size_t)(n0 + srB0) * K + soB0 * 8;
    const U16* BgB1 = Bt + (size_t)(n0 + srB1) * K + soB1 * 8;
    const U16* BgB2 = Bt + (size_t)(n0 + srB2) * K + soB2 * 8;
    const U16* BgB3 = Bt + (size_t)(n0 + srB3) * K + soB3 * 8;

    auto stAf = [&](int kt, U16* d) {               // 2 loads
        gld16(AgA0 + kt * 64, d + cA0 * 8);
        gld16(AgA1 + kt * 64, d + cA1 * 8);
    };
    auto stBf = [&](int kt, U16* d) {               // 4 loads
        gld16(BgB0 + kt * 64, d + cB0 * 8);
        gld16(BgB1 + kt * 64, d + cB1 * 8);
        gld16(BgB2 + kt * 64, d + cB2 * 8);
        gld16(BgB3 + kt * 64, d + cB3 * 8);
    };

    const int as0 = (quad ^ (l15 & 7)) * 8;
    const int as1 = ((4 + quad) ^ (l15 & 7)) * 8;
    const int nk = K >> 6;                          // 16

    auto ktile = [&](const U16* Ac, const U16* Bc, U16* An, U16* Bn, int kt) {
        const bool nx = (kt + 1) < nk;
        if (nx) {
            stAf(kt + 1, An);
            stBf(kt + 1, Bn);
            asm volatile("s_waitcnt vmcnt(6)" ::: "memory");
        } else {
            asm volatile("s_waitcnt vmcnt(0)" ::: "memory");
        }
        __builtin_amdgcn_s_barrier();
        asm volatile("" ::: "memory");
        bf16x8 af[2][2], bfr[4][2];
#pragma unroll
        for (int i = 0; i < 2; i++) {
            af[i][0] = *(const bf16x8*)&Ac[(wm + i * 16 + l15) * 64 + as0];
            af[i][1] = *(const bf16x8*)&Ac[(wm + i * 16 + l15) * 64 + as1];
        }
#pragma unroll
        for (int j = 0; j < 4; j++) {
            bfr[j][0] = *(const bf16x8*)&Bc[(wn + j * 16 + l15) * 64 + as0];
            bfr[j][1] = *(const bf16x8*)&Bc[(wn + j * 16 + l15) * 64 + as1];
        }
        __builtin_amdgcn_s_setprio(1);
#pragma unroll
        for (int i = 0; i < 2; i++)
#pragma unroll
            for (int j = 0; j < 4; j++) {
                acc[i][j] = __builtin_amdgcn_mfma_f32_16x16x32_bf16(af[i][0], bfr[j][0], acc[i][j], 0, 0, 0);
                acc[i][j] = __builtin_amdgcn_mfma_f32_16x16x32_bf16(af[i][1], bfr[j][1], acc[i][j], 0, 0, 0);
            }
        __builtin_amdgcn_s_setprio(0);
        asm volatile("" ::: "memory");
        __builtin_amdgcn_s_barrier();
        asm volatile("" ::: "memory");
    };

    stAf(0, &As[0][0]);
    stBf(0, &Bs[0][0]);

    for (int kt = 0; kt < nk; kt += 2) {
        ktile(&As[0][0], &Bs[0][0], &As[1][0], &Bs[1][0], kt);
        ktile(&As[1][0], &Bs[1][0], &As[0][0], &Bs[0][0], kt + 1);
    }

#pragma unroll
    for (int i = 0; i < 2; i++) {
#pragma unroll
        for (int j = 0; j < 4; j++) {
            int col = n0 + wn + j * 16 + l15;
            float bv = bias[col];
#pragma unroll
            for (int r = 0; r < 4; r++) {
                int row = m0 + wm + i * 16 + quad * 4 + r;
                C[(size_t)row * N + col] = acc[i][j][r] + bv;
            }
        }
    }
}

// ---- MFMA flash attention, in-register softmax (r7-proven 54us, parked) ---
__global__ __launch_bounds__(256) void attn_kernel(const U16* __restrict__ qkv,
                                                   const U16* __restrict__ vT,
                                                   U16* __restrict__ attn_out) {
    const int p = blockIdx.x;                    // 0..511
    const int xcd = p & 7;
    const int slot = p >> 3;                     // 0..63 within XCD
    const int bh = ((slot & 3) << 3) | xcd;      // bh & 7 == XCD id
    const int qt = slot >> 2;                    // 0..15, 128 q-rows per block
    const int b = bh >> 4, h = bh & 15;
    const int t = threadIdx.x;
    const int wave = t >> 6, lane = t & 63;
    const int l31 = lane & 31, hi = lane >> 5;
    const float sc2 = 0.125f * 1.44269504089f;  // scale * log2(e)

    __shared__ __align__(16) U16 Kt[2][64 * 64];    // [key][d-swizzled]
    __shared__ __align__(16) U16 Vt[2][64 * 64];    // [d][key-swizzled]

    const size_t base = (size_t)(b * 2048) * 3072;
    const U16* vTbh = vT + ((size_t)(b * 16 + h) * 64) * 2048;

    // Q fragments, pre-scaled by sc2 (softmax = exp2(S) with no per-iter mul)
    bf16x8 qf[4];
    {
        int qrow = qt * 128 + wave * 32 + l31;
        const U16* qp = qkv + base + (size_t)qrow * 3072 + h * 64 + hi * 8;
#pragma unroll
        for (int s = 0; s < 4; s++) {
            union { bf16x8 v; U16 u[8]; } a;
            a.v = *(const bf16x8*)&qp[s * 16];
#pragma unroll
            for (int e = 0; e < 8; e++) a.u[e] = f2b(b2f(a.u[e]) * sc2);
            qf[s] = a.v;
        }
    }

    float l4[4] = { 0.f, 0.f, 0.f, 0.f };
    f32x16 oacc[2];  // O^T[d][q]: d = db*32 + (reg&3)+8*(reg>>2)+4*hi, q=l31
#pragma unroll
    for (int db = 0; db < 2; db++)
#pragma unroll
        for (int r = 0; r < 16; r++)
            oacc[db][r] = 0.0f;

    const int c0 = t, c1 = 256 + t;
    const int row0 = c0 >> 3, oct0 = (c0 & 7) ^ (row0 & 7);
    const int row1 = c1 >> 3, oct1 = (c1 & 7) ^ (row1 & 7);

    gld16(&qkv[base + (size_t)row0 * 3072 + 1024 + h * 64 + oct0 * 8], &Kt[0][c0 * 8]);
    gld16(&qkv[base + (size_t)row1 * 3072 + 1024 + h * 64 + oct1 * 8], &Kt[0][c1 * 8]);
    gld16(&vTbh[(size_t)row0 * 2048 + oct0 * 8], &Vt[0][c0 * 8]);
    gld16(&vTbh[(size_t)row1 * 2048 + oct1 * 8], &Vt[0][c1 * 8]);
    __syncthreads();

    auto step = [&](const U16* KtC, const U16* VtC, U16* KtN, U16* VtN, int nt) {
        gld16(&qkv[base + (size_t)(nt * 64 + row0) * 3072 + 1024 + h * 64 + oct0 * 8], &KtN[c0 * 8]);
        gld16(&qkv[base + (size_t)(nt * 64 + row1) * 3072 + 1024 + h * 64 + oct1 * 8], &KtN[c1 * 8]);
        gld16(&vTbh[(size_t)row0 * 2048 + nt * 64 + oct0 * 8], &VtN[c0 * 8]);
        gld16(&vTbh[(size_t)row1 * 2048 + nt * 64 + oct1 * 8], &VtN[c1 * 8]);
#pragma unroll
        for (int kb = 0; kb < 2; kb++) {
            bf16x8 kf[4];
#pragma unroll
            for (int s = 0; s < 4; s++)
                kf[s] = *(const bf16x8*)&KtC[(kb * 32 + l31) * 64 +
                                             (((s * 2 + hi) ^ (l31 & 7)) * 8)];
            bf16x8 vfr[2][2];
#pragma unroll
            for (int db = 0; db < 2; db++)
#pragma unroll
                for (int s = 0; s < 2; s++)
                    vfr[db][s] = *(const bf16x8*)&VtC[(db * 32 + l31) * 64 +
                                                      (((kb * 4 + s * 2 + hi) ^ (l31 & 7)) * 8)];

            f32x16 st = {0.f, 0.f, 0.f, 0.f, 0.f, 0.f, 0.f, 0.f,
                         0.f, 0.f, 0.f, 0.f, 0.f, 0.f, 0.f, 0.f};
            __builtin_amdgcn_s_setprio(1);
#pragma unroll
            for (int s = 0; s < 4; s++)
                st = __builtin_amdgcn_mfma_f32_32x32x16_bf16(kf[s], qf[s], st, 0, 0, 0);
            __builtin_amdgcn_s_setprio(0);

            float pe[16];
#pragma unroll
            for (int r = 0; r < 16; r++) {
                pe[r] = __builtin_amdgcn_exp2f(st[r]);
                l4[r & 3] += pe[r];
            }

#pragma unroll
            for (int s = 0; s < 2; s++) {
                unsigned p01 = cvt_pk(pe[s * 8 + 0], pe[s * 8 + 1]);
                unsigned p23 = cvt_pk(pe[s * 8 + 2], pe[s * 8 + 3]);
                unsigned p45 = cvt_pk(pe[s * 8 + 4], pe[s * 8 + 5]);
                unsigned p67 = cvt_pk(pe[s * 8 + 6], pe[s * 8 + 7]);
                plswap(p01, p45);
                plswap(p23, p67);
                union { unsigned u[4]; bf16x8 v; } pw;
                pw.u[0] = p01; pw.u[1] = p23; pw.u[2] = p45; pw.u[3] = p67;
                __builtin_amdgcn_s_setprio(1);
#pragma unroll
                for (int db = 0; db < 2; db++)
                    oacc[db] = __builtin_amdgcn_mfma_f32_32x32x16_bf16(
                        vfr[db][s], pw.v, oacc[db], 0, 0, 0);
                __builtin_amdgcn_s_setprio(0);
            }
        }
        __syncthreads();
    };

    for (int kt2 = 0; kt2 < 16; kt2++) {
        step(&Kt[0][0], &Vt[0][0], &Kt[1][0], &Vt[1][0], 2 * kt2 + 1);
        step(&Kt[1][0], &Vt[1][0], &Kt[0][0], &Vt[0][0], (2 * kt2 + 2) & 31);
    }

    float l_acc = (l4[0] + l4[1]) + (l4[2] + l4[3]);
    float lt = l_acc + __shfl_xor(l_acc, 32);
    float inv = 1.0f / lt;
    int qrow = b * 2048 + qt * 128 + wave * 32 + l31;
#pragma unroll
    for (int db = 0; db < 2; db++) {
#pragma unroll
        for (int g = 0; g < 4; g++) {
            ushort4 stv;
            stv.x = f2b(oacc[db][g * 4 + 0] * inv);
            stv.y = f2b(oacc[db][g * 4 + 1] * inv);
            stv.z = f2b(oacc[db][g * 4 + 2] * inv);
            stv.w = f2b(oacc[db][g * 4 + 3] * inv);
            int col = h * 64 + db * 32 + g * 8 + hi * 4;
            *(ushort4*)&attn_out[(size_t)qrow * 1024 + col] = stv;
        }
    }
}

extern "C" void kernel_launch(void* const* d_in, const int* in_sizes, int n_in,
                              void* d_out, int out_size, void* d_ws, size_t ws_size,
                              hipStream_t stream) {
    (void)in_sizes; (void)n_in; (void)out_size; (void)ws_size;
    const float* x    = (const float*)d_in[0];
    const float* g    = (const float*)d_in[1];
    const float* be   = (const float*)d_in[2];
    const float* Wqkv = (const float*)d_in[3];
    const float* Wout = (const float*)d_in[4];
    const float* bout = (const float*)d_in[5];
    float* out = (float*)d_out;   // reference output dtype is fp32
    char* ws = (char*)d_ws;

    U16* xn   = (U16*)(ws);                          // 8 MB, reused as aout
    U16* qkv  = (U16*)(ws + (size_t)(8u  << 20));    // 24 MB (V third unused)
    U16* WqT  = (U16*)(ws + (size_t)(32u << 20));    // 6 MB
    U16* WoT  = (U16*)(ws + (size_t)(38u << 20));    // 2 MB
    U16* vT   = (U16*)(ws + (size_t)(40u << 20));    // 8 MB: V transposed
    U16* aout = xn;  // xn dead after GEMM1

    prep_kernel<<<8192, 256, 0, stream>>>(x, g, be, xn, Wqkv, WqT, Wout, WoT);
    gemm_g1<<<256, 512, 0, stream>>>(xn, WqT, qkv, vT, 4096, 3072, 1024);
    attn_kernel<<<512, 256, 0, stream>>>(qkv, vT, aout);
    gemm_bt2<<<dim3(1024 / 128, 4096 / 64), 256, 0, stream>>>(aout, WoT, bout, out, 4096, 1024, 1024);
}

// Round 12
// 180.379 us; speedup vs baseline: 1.0225x; 1.0225x over previous
//
#include <hip/hip_runtime.h>

typedef unsigned short U16;
typedef __bf16 bf16x8 __attribute__((ext_vector_type(8)));
typedef float f32x4 __attribute__((ext_vector_type(4)));
typedef float f32x16 __attribute__((ext_vector_type(16)));

__device__ inline float b2f(U16 u) {
    union { unsigned int i; float f; } v;
    v.i = ((unsigned int)u) << 16;
    return v.f;
}
__device__ inline U16 f2b(float f) {
    union { float f; unsigned int u; } v;
    v.f = f;
    unsigned int r = (v.u + 0x7fffu + ((v.u >> 16) & 1u)) >> 16;
    return (U16)r;
}

// pack two f32 -> two bf16 in one u32 (RNE, same as f2b)
__device__ inline unsigned cvt_pk(float lo, float hi) {
    unsigned d;
    asm("v_cvt_pk_bf16_f32 %0, %1, %2" : "=v"(d) : "v"(lo), "v"(hi));
    return d;
}
// swap: a[lanes 32-63] <-> b[lanes 0-31]
__device__ inline void plswap(unsigned &a, unsigned &b) {
    asm("v_permlane32_swap_b32 %0, %1" : "+v"(a), "+v"(b));
}

// async global->LDS, 16B per lane (LDS dest = wave-uniform base + lane*16)
__device__ inline void gld16(const void* g, void* l) {
    __builtin_amdgcn_global_load_lds(
        (const __attribute__((address_space(1))) void*)g,
        (__attribute__((address_space(3))) void*)l, 16, 0, 0);
}

// ------- prep: LN (blocks 0..4095) + two weight transposes, ONE launch -----
__global__ __launch_bounds__(256) void prep_kernel(const float* __restrict__ x,
                                                   const float* __restrict__ gamma,
                                                   const float* __restrict__ beta,
                                                   U16* __restrict__ xn,
                                                   const float* __restrict__ Wqkv,
                                                   U16* __restrict__ WqT,
                                                   const float* __restrict__ Wout,
                                                   U16* __restrict__ WoT) {
    int p = blockIdx.x;
    int t = threadIdx.x;
    if (p < 4096) {
        // ---- LayerNorm row p: fp32 -> bf16 ----
        int row = p;
        float4 raw = ((const float4*)(x + (size_t)row * 1024))[t];
        float v[4] = { raw.x, raw.y, raw.z, raw.w };
        float s = v[0] + v[1] + v[2] + v[3];
        float s2 = v[0] * v[0] + v[1] * v[1] + v[2] * v[2] + v[3] * v[3];
#pragma unroll
        for (int off = 32; off >= 1; off >>= 1) {
            s  += __shfl_xor(s,  off);
            s2 += __shfl_xor(s2, off);
        }
        __shared__ float red[8];
        if ((t & 63) == 0) { red[(t >> 6) * 2] = s; red[(t >> 6) * 2 + 1] = s2; }
        __syncthreads();
        float S  = red[0] + red[2] + red[4] + red[6];
        float S2 = red[1] + red[3] + red[5] + red[7];
        float mu = S * (1.0f / 1024.0f);
        float var = S2 * (1.0f / 1024.0f) - mu * mu;
        float rstd = rsqrtf(var + 1e-5f);
        float4 g4 = ((const float4*)gamma)[t];
        float4 b4 = ((const float4*)beta)[t];
        ushort4 o;
        o.x = f2b((v[0] - mu) * rstd * g4.x + b4.x);
        o.y = f2b((v[1] - mu) * rstd * g4.y + b4.y);
        o.z = f2b((v[2] - mu) * rstd * g4.z + b4.z);
        o.w = f2b((v[3] - mu) * rstd * g4.w + b4.w);
        ((ushort4*)(xn + (size_t)row * 1024))[t] = o;
        return;
    }
    // ---- transpose + f2b: out[c][r] = bf16(in[r][c]) ----
    p -= 4096;
    const float* in; U16* out; int C, tilesx;
    if (p < 3072) { in = Wqkv; out = WqT; C = 3072; tilesx = 96; }
    else { p -= 3072; in = Wout; out = WoT; C = 1024; tilesx = 32; }
    const int R = 1024;
    int c0 = (p % tilesx) * 32, r0 = (p / tilesx) * 32;
    int tx = t & 31, ty = t >> 5;   // 32 x 8
    __shared__ float tile[32][33];
#pragma unroll
    for (int i = 0; i < 32; i += 8)
        tile[ty + i][tx] = in[(size_t)(r0 + ty + i) * C + c0 + tx];
    __syncthreads();
#pragma unroll
    for (int i = 0; i < 32; i += 8)
        out[(size_t)(c0 + ty + i) * R + r0 + tx] = f2b(tile[tx][ty + i]);
}

// ------ GEMM1: 256x192 tile, BK=64, 8 waves, counted-vmcnt pipeline.
// r9 schedule (proven 181.0us): stA(t+1) at top with vmcnt(4) [entry 7 =
// A(t)4+B(t)3; +4 = 11; retire 7 = tile t], stB(t+1) issued mid-tile,
// spreading DMA issue across the tile (r10's all-at-top variant regressed).
// ONE change vs r9: the mid-tile barrier (between P0 and P1) is REMOVED —
// P0 and P1 both read only the CURRENT buffer (no cross-wave hazard); the
// barriers that matter are (a) post-vmcnt (all waves' loads retired before
// any wave reads the tile) and (b) tile-end (all reads done before next
// tile's DMA overwrites this buffer; each wave's ds_reads are lgkm-retired
// before its MFMAs, hence before it reaches the end barrier). Saves 16
// barrier drains per block. Barrier count is wave-uniform — no hang path.
// Oct swizzle + XCD decode unchanged (full-chip 256 blocks).
__global__ __launch_bounds__(512) void gemm_g1(const U16* __restrict__ A,
                                               const U16* __restrict__ Bt,
                                               U16* __restrict__ C,
                                               U16* __restrict__ vT,
                                               int M, int N, int K) {
    __shared__ __align__(16) U16 As[2][2][128 * 64];   // 64 KB
    __shared__ __align__(16) U16 Bs[2][192 * 64];      // 48 KB
    const int p = blockIdx.x;
    const int xcd = p & 7, sl = p >> 3;              // sl in 0..31
    const int by = xcd * 2 + (sl >> 4);
    const int bx = sl & 15;
    const int m0 = by * 256, n0 = bx * 192;
    const int t = threadIdx.x;
    const int wave = t >> 6, lane = t & 63, l15 = lane & 15, quad = lane >> 4;
    const int wm = wave >> 2, wn = wave & 3;

    f32x4 acc[8][3];
#pragma unroll
    for (int i = 0; i < 8; i++)
#pragma unroll
        for (int j = 0; j < 3; j++)
            acc[i][j] = (f32x4){0.f, 0.f, 0.f, 0.f};

    // A staging: 2048 chunks per 256-row tile (2 halves x 1024), 4/thread
    const int c0 = t, c1 = 512 + t;
    const int sr0 = c0 >> 3, so0 = (c0 & 7) ^ (sr0 & 7);
    const int sr1 = c1 >> 3, so1 = (c1 & 7) ^ (sr1 & 7);
    const U16* Ag0 = A + (size_t)(m0 + sr0) * K + so0 * 8;
    const U16* Ag1 = A + (size_t)(m0 + sr1) * K + so1 * 8;
    const size_t hstep = (size_t)128 * K;           // +128 rows

    // B staging: 1536 chunks per 192-row tile, 3/thread
    const int cb2 = 1024 + t;
    const int sb2 = cb2 >> 3, ob2 = (cb2 & 7) ^ (sb2 & 7);
    const U16* Bg0 = Bt + (size_t)(n0 + sr0) * K + so0 * 8;   // chunk t
    const U16* Bg1 = Bt + (size_t)(n0 + sr1) * K + so1 * 8;   // chunk 512+t
    const U16* Bg2 = Bt + (size_t)(n0 + sb2) * K + ob2 * 8;   // chunk 1024+t

    auto stA = [&](int kt, U16* d0, U16* d1) {      // 4 loads
        gld16(Ag0 + kt * 64, d0 + c0 * 8);
        gld16(Ag1 + kt * 64, d0 + c1 * 8);
        gld16(Ag0 + hstep + kt * 64, d1 + c0 * 8);
        gld16(Ag1 + hstep + kt * 64, d1 + c1 * 8);
    };
    auto stB = [&](int kt, U16* d) {                // 3 loads
        gld16(Bg0 + kt * 64, d + c0 * 8);
        gld16(Bg1 + kt * 64, d + c1 * 8);
        gld16(Bg2 + kt * 64, d + cb2 * 8);
    };

    // frag-read offsets (elements): k 0..31 -> oct quad, k 32..63 -> 4+quad
    const int slot0 = quad ^ (l15 & 7);
    const int slot1 = (4 + quad) ^ (l15 & 7);
    const int aoff0 = l15 * 64 + slot0 * 8, aoff1 = l15 * 64 + slot1 * 8;
    const int boff0 = wn * 48 * 64 + aoff0, boff1 = wn * 48 * 64 + aoff1;
    const int nk = K >> 6;                          // 16

    auto ktile = [&](const U16* Ac0, const U16* Ac1, const U16* Bc,
                     U16* An0, U16* An1, U16* Bn, int kt) {
        const bool nx = (kt + 1) < nk;
        if (nx) {
            stA(kt + 1, An0, An1);
            asm volatile("s_waitcnt vmcnt(4)" ::: "memory");
        } else {
            asm volatile("s_waitcnt vmcnt(0)" ::: "memory");
        }
        __builtin_amdgcn_s_barrier();
        asm volatile("" ::: "memory");
        const U16* Ah = wm ? Ac1 : Ac0;
        bf16x8 bfr[3][2], af[4][2];
#pragma unroll
        for (int j = 0; j < 3; j++) {
            bfr[j][0] = *(const bf16x8*)&Bc[j * 16 * 64 + boff0];
            bfr[j][1] = *(const bf16x8*)&Bc[j * 16 * 64 + boff1];
        }
#pragma unroll
        for (int i = 0; i < 4; i++) {
            af[i][0] = *(const bf16x8*)&Ah[i * 16 * 64 + aoff0];
            af[i][1] = *(const bf16x8*)&Ah[i * 16 * 64 + aoff1];
        }
        if (nx) stB(kt + 1, Bn);
        __builtin_amdgcn_s_setprio(1);
#pragma unroll
        for (int i = 0; i < 4; i++)
#pragma unroll
            for (int j = 0; j < 3; j++) {
                acc[i][j] = __builtin_amdgcn_mfma_f32_16x16x32_bf16(af[i][0], bfr[j][0], acc[i][j], 0, 0, 0);
                acc[i][j] = __builtin_amdgcn_mfma_f32_16x16x32_bf16(af[i][1], bfr[j][1], acc[i][j], 0, 0, 0);
            }
        __builtin_amdgcn_s_setprio(0);
        // (mid-tile barrier removed: P1 reads the same buffer as P0 — no
        //  cross-wave hazard; the end barrier below re-syncs for buf reuse)
#pragma unroll
        for (int i = 0; i < 4; i++) {
            af[i][0] = *(const bf16x8*)&Ah[(4 + i) * 16 * 64 + aoff0];
            af[i][1] = *(const bf16x8*)&Ah[(4 + i) * 16 * 64 + aoff1];
        }
        __builtin_amdgcn_s_setprio(1);
#pragma unroll
        for (int i = 0; i < 4; i++)
#pragma unroll
            for (int j = 0; j < 3; j++) {
                acc[4 + i][j] = __builtin_amdgcn_mfma_f32_16x16x32_bf16(af[i][0], bfr[j][0], acc[4 + i][j], 0, 0, 0);
                acc[4 + i][j] = __builtin_amdgcn_mfma_f32_16x16x32_bf16(af[i][1], bfr[j][1], acc[4 + i][j], 0, 0, 0);
            }
        __builtin_amdgcn_s_setprio(0);
        asm volatile("" ::: "memory");
        __builtin_amdgcn_s_barrier();
        asm volatile("" ::: "memory");
    };

    // prologue: tile 0 -> buf 0, full drain once
    stA(0, &As[0][0][0], &As[0][1][0]);
    stB(0, &Bs[0][0]);
    asm volatile("s_waitcnt vmcnt(0)" ::: "memory");
    __builtin_amdgcn_s_barrier();
    asm volatile("" ::: "memory");

    for (int kt = 0; kt < nk; kt += 2) {
        ktile(&As[0][0][0], &As[0][1][0], &Bs[0][0],
              &As[1][0][0], &As[1][1][0], &Bs[1][0], kt);
        ktile(&As[1][0][0], &As[1][1][0], &Bs[1][0],
              &As[0][0][0], &As[0][1][0], &Bs[0][0], kt + 1);
    }

    // epilogue: per-j V-vs-C branch (j-blocks are 16-aligned; 2048 % 16 == 0)
#pragma unroll
    for (int j = 0; j < 3; j++) {
        int cb = n0 + wn * 48 + j * 16;
        if (vT && cb >= 2048) {
#pragma unroll
            for (int i = 0; i < 8; i++) {
                int col = cb + l15 - 2048;
                int hh = col >> 6, dd = col & 63;
                int row0 = m0 + wm * 128 + i * 16 + quad * 4;
                int bb = row0 >> 11, nn = row0 & 2047;
                ushort4 st;
                st.x = f2b(acc[i][j][0]); st.y = f2b(acc[i][j][1]);
                st.z = f2b(acc[i][j][2]); st.w = f2b(acc[i][j][3]);
                *(ushort4*)&vT[((((size_t)bb * 16) + hh) * 64 + dd) * 2048 + nn] = st;
            }
        } else {
#pragma unroll
            for (int i = 0; i < 8; i++) {
                int col = cb + l15;
                int row0 = m0 + wm * 128 + i * 16 + quad * 4;
#pragma unroll
                for (int r = 0; r < 4; r++)
                    C[(size_t)(row0 + r) * N + col] = f2b(acc[i][j][r]);
            }
        }
    }
}

// ------ GEMM2: 64x128 tile, BK=64, counted-vmcnt pipeline (r9 schedule:
// stAf at top with vmcnt(2), stBf mid-tile — proven; r10's all-at-top
// variant regressed).
__global__ __launch_bounds__(256) void gemm_bt2(const U16* __restrict__ A,
                                                const U16* __restrict__ Bt,
                                                const float* __restrict__ bias,
                                                float* __restrict__ C,
                                                int M, int N, int K) {
    __shared__ __align__(16) U16 As[2][64 * 64];
    __shared__ __align__(16) U16 Bs[2][128 * 64];
    const int m0 = blockIdx.y * 64, n0 = blockIdx.x * 128;
    const int t = threadIdx.x;
    const int wave = t >> 6, lane = t & 63, l15 = lane & 15, quad = lane >> 4;
    const int wm = (wave >> 1) * 32, wn = (wave & 1) * 64;

    f32x4 acc[2][4];
#pragma unroll
    for (int i = 0; i < 2; i++)
#pragma unroll
        for (int j = 0; j < 4; j++)
            acc[i][j] = (f32x4){0.f, 0.f, 0.f, 0.f};

    const int cA0 = t, cA1 = 256 + t;
    const int srA0 = cA0 >> 3, soA0 = (cA0 & 7) ^ (srA0 & 7);
    const int srA1 = cA1 >> 3, soA1 = (cA1 & 7) ^ (srA1 & 7);
    const U16* AgA0 = A + (size_t)(m0 + srA0) * K + soA0 * 8;
    const U16* AgA1 = A + (size_t)(m0 + srA1) * K + soA1 * 8;
    const int cB0 = t, cB1 = 256 + t, cB2 = 512 + t, cB3 = 768 + t;
    const int srB0 = cB0 >> 3, soB0 = (cB0 & 7) ^ (srB0 & 7);
    const int srB1 = cB1 >> 3, soB1 = (cB1 & 7) ^ (srB1 & 7);
    const int srB2 = cB2 >> 3, soB2 = (cB2 & 7) ^ (srB2 & 7);
    const int srB3 = cB3 >> 3, soB3 = (cB3 & 7) ^ (srB3 & 7);
    const U16* BgB0 = Bt + (size_t)(n0 + srB0) * K + soB0 * 8;
    const U16* BgB1 = Bt + (size_t)(n0 + srB1) * K + soB1 * 8;
    const U16* BgB2 = Bt + (size_t)(n0 + srB2) * K + soB2 * 8;
    const U16* BgB3 = Bt + (size_t)(n0 + srB3) * K + soB3 * 8;

    auto stAf = [&](int kt, U16* d) {               // 2 loads
        gld16(AgA0 + kt * 64, d + cA0 * 8);
        gld16(AgA1 + kt * 64, d + cA1 * 8);
    };
    auto stBf = [&](int kt, U16* d) {               // 4 loads
        gld16(BgB0 + kt * 64, d + cB0 * 8);
        gld16(BgB1 + kt * 64, d + cB1 * 8);
        gld16(BgB2 + kt * 64, d + cB2 * 8);
        gld16(BgB3 + kt * 64, d + cB3 * 8);
    };

    const int as0 = (quad ^ (l15 & 7)) * 8;
    const int as1 = ((4 + quad) ^ (l15 & 7)) * 8;
    const int nk = K >> 6;                          // 16

    auto ktile = [&](const U16* Ac, const U16* Bc, U16* An, U16* Bn, int kt) {
        const bool nx = (kt + 1) < nk;
        if (nx) {
            stAf(kt + 1, An);
            asm volatile("s_waitcnt vmcnt(2)" ::: "memory");
        } else {
            asm volatile("s_waitcnt vmcnt(0)" ::: "memory");
        }
        __builtin_amdgcn_s_barrier();
        asm volatile("" ::: "memory");
        bf16x8 af[2][2], bfr[4][2];
#pragma unroll
        for (int i = 0; i < 2; i++) {
            af[i][0] = *(const bf16x8*)&Ac[(wm + i * 16 + l15) * 64 + as0];
            af[i][1] = *(const bf16x8*)&Ac[(wm + i * 16 + l15) * 64 + as1];
        }
#pragma unroll
        for (int j = 0; j < 4; j++) {
            bfr[j][0] = *(const bf16x8*)&Bc[(wn + j * 16 + l15) * 64 + as0];
            bfr[j][1] = *(const bf16x8*)&Bc[(wn + j * 16 + l15) * 64 + as1];
        }
        if (nx) stBf(kt + 1, Bn);
        __builtin_amdgcn_s_setprio(1);
#pragma unroll
        for (int i = 0; i < 2; i++)
#pragma unroll
            for (int j = 0; j < 4; j++) {
                acc[i][j] = __builtin_amdgcn_mfma_f32_16x16x32_bf16(af[i][0], bfr[j][0], acc[i][j], 0, 0, 0);
                acc[i][j] = __builtin_amdgcn_mfma_f32_16x16x32_bf16(af[i][1], bfr[j][1], acc[i][j], 0, 0, 0);
            }
        __builtin_amdgcn_s_setprio(0);
        asm volatile("" ::: "memory");
        __builtin_amdgcn_s_barrier();
        asm volatile("" ::: "memory");
    };

    stAf(0, &As[0][0]);
    stBf(0, &Bs[0][0]);
    asm volatile("s_waitcnt vmcnt(0)" ::: "memory");
    __builtin_amdgcn_s_barrier();
    asm volatile("" ::: "memory");

    for (int kt = 0; kt < nk; kt += 2) {
        ktile(&As[0][0], &Bs[0][0], &As[1][0], &Bs[1][0], kt);
        ktile(&As[1][0], &Bs[1][0], &As[0][0], &Bs[0][0], kt + 1);
    }

#pragma unroll
    for (int i = 0; i < 2; i++) {
#pragma unroll
        for (int j = 0; j < 4; j++) {
            int col = n0 + wn + j * 16 + l15;
            float bv = bias[col];
#pragma unroll
            for (int r = 0; r < 4; r++) {
                int row = m0 + wm + i * 16 + quad * 4 + r;
                C[(size_t)row * N + col] = acc[i][j][r] + bv;
            }
        }
    }
}

// ---- MFMA flash attention, in-register softmax (r7-proven 54us, parked) ---
__global__ __launch_bounds__(256) void attn_kernel(const U16* __restrict__ qkv,
                                                   const U16* __restrict__ vT,
                                                   U16* __restrict__ attn_out) {
    const int p = blockIdx.x;                    // 0..511
    const int xcd = p & 7;
    const int slot = p >> 3;                     // 0..63 within XCD
    const int bh = ((slot & 3) << 3) | xcd;      // bh & 7 == XCD id
    const int qt = slot >> 2;                    // 0..15, 128 q-rows per block
    const int b = bh >> 4, h = bh & 15;
    const int t = threadIdx.x;
    const int wave = t >> 6, lane = t & 63;
    const int l31 = lane & 31, hi = lane >> 5;
    const float sc2 = 0.125f * 1.44269504089f;  // scale * log2(e)

    __shared__ __align__(16) U16 Kt[2][64 * 64];    // [key][d-swizzled]
    __shared__ __align__(16) U16 Vt[2][64 * 64];    // [d][key-swizzled]

    const size_t base = (size_t)(b * 2048) * 3072;
    const U16* vTbh = vT + ((size_t)(b * 16 + h) * 64) * 2048;

    // Q fragments, pre-scaled by sc2 (softmax = exp2(S) with no per-iter mul)
    bf16x8 qf[4];
    {
        int qrow = qt * 128 + wave * 32 + l31;
        const U16* qp = qkv + base + (size_t)qrow * 3072 + h * 64 + hi * 8;
#pragma unroll
        for (int s = 0; s < 4; s++) {
            union { bf16x8 v; U16 u[8]; } a;
            a.v = *(const bf16x8*)&qp[s * 16];
#pragma unroll
            for (int e = 0; e < 8; e++) a.u[e] = f2b(b2f(a.u[e]) * sc2);
            qf[s] = a.v;
        }
    }

    float l4[4] = { 0.f, 0.f, 0.f, 0.f };
    f32x16 oacc[2];  // O^T[d][q]: d = db*32 + (reg&3)+8*(reg>>2)+4*hi, q=l31
#pragma unroll
    for (int db = 0; db < 2; db++)
#pragma unroll
        for (int r = 0; r < 16; r++)
            oacc[db][r] = 0.0f;

    const int c0 = t, c1 = 256 + t;
    const int row0 = c0 >> 3, oct0 = (c0 & 7) ^ (row0 & 7);
    const int row1 = c1 >> 3, oct1 = (c1 & 7) ^ (row1 & 7);

    gld16(&qkv[base + (size_t)row0 * 3072 + 1024 + h * 64 + oct0 * 8], &Kt[0][c0 * 8]);
    gld16(&qkv[base + (size_t)row1 * 3072 + 1024 + h * 64 + oct1 * 8], &Kt[0][c1 * 8]);
    gld16(&vTbh[(size_t)row0 * 2048 + oct0 * 8], &Vt[0][c0 * 8]);
    gld16(&vTbh[(size_t)row1 * 2048 + oct1 * 8], &Vt[0][c1 * 8]);
    __syncthreads();

    auto step = [&](const U16* KtC, const U16* VtC, U16* KtN, U16* VtN, int nt) {
        gld16(&qkv[base + (size_t)(nt * 64 + row0) * 3072 + 1024 + h * 64 + oct0 * 8], &KtN[c0 * 8]);
        gld16(&qkv[base + (size_t)(nt * 64 + row1) * 3072 + 1024 + h * 64 + oct1 * 8], &KtN[c1 * 8]);
        gld16(&vTbh[(size_t)row0 * 2048 + nt * 64 + oct0 * 8], &VtN[c0 * 8]);
        gld16(&vTbh[(size_t)row1 * 2048 + nt * 64 + oct1 * 8], &VtN[c1 * 8]);
#pragma unroll
        for (int kb = 0; kb < 2; kb++) {
            bf16x8 kf[4];
#pragma unroll
            for (int s = 0; s < 4; s++)
                kf[s] = *(const bf16x8*)&KtC[(kb * 32 + l31) * 64 +
                                             (((s * 2 + hi) ^ (l31 & 7)) * 8)];
            bf16x8 vfr[2][2];
#pragma unroll
            for (int db = 0; db < 2; db++)
#pragma unroll
                for (int s = 0; s < 2; s++)
                    vfr[db][s] = *(const bf16x8*)&VtC[(db * 32 + l31) * 64 +
                                                      (((kb * 4 + s * 2 + hi) ^ (l31 & 7)) * 8)];

            f32x16 st = {0.f, 0.f, 0.f, 0.f, 0.f, 0.f, 0.f, 0.f,
                         0.f, 0.f, 0.f, 0.f, 0.f, 0.f, 0.f, 0.f};
            __builtin_amdgcn_s_setprio(1);
#pragma unroll
            for (int s = 0; s < 4; s++)
                st = __builtin_amdgcn_mfma_f32_32x32x16_bf16(kf[s], qf[s], st, 0, 0, 0);
            __builtin_amdgcn_s_setprio(0);

            float pe[16];
#pragma unroll
            for (int r = 0; r < 16; r++) {
                pe[r] = __builtin_amdgcn_exp2f(st[r]);
                l4[r & 3] += pe[r];
            }

#pragma unroll
            for (int s = 0; s < 2; s++) {
                unsigned p01 = cvt_pk(pe[s * 8 + 0], pe[s * 8 + 1]);
                unsigned p23 = cvt_pk(pe[s * 8 + 2], pe[s * 8 + 3]);
                unsigned p45 = cvt_pk(pe[s * 8 + 4], pe[s * 8 + 5]);
                unsigned p67 = cvt_pk(pe[s * 8 + 6], pe[s * 8 + 7]);
                plswap(p01, p45);
                plswap(p23, p67);
                union { unsigned u[4]; bf16x8 v; } pw;
                pw.u[0] = p01; pw.u[1] = p23; pw.u[2] = p45; pw.u[3] = p67;
                __builtin_amdgcn_s_setprio(1);
#pragma unroll
                for (int db = 0; db < 2; db++)
                    oacc[db] = __builtin_amdgcn_mfma_f32_32x32x16_bf16(
                        vfr[db][s], pw.v, oacc[db], 0, 0, 0);
                __builtin_amdgcn_s_setprio(0);
            }
        }
        __syncthreads();
    };

    for (int kt2 = 0; kt2 < 16; kt2++) {
        step(&Kt[0][0], &Vt[0][0], &Kt[1][0], &Vt[1][0], 2 * kt2 + 1);
        step(&Kt[1][0], &Vt[1][0], &Kt[0][0], &Vt[0][0], (2 * kt2 + 2) & 31);
    }

    float l_acc = (l4[0] + l4[1]) + (l4[2] + l4[3]);
    float lt = l_acc + __shfl_xor(l_acc, 32);
    float inv = 1.0f / lt;
    int qrow = b * 2048 + qt * 128 + wave * 32 + l31;
#pragma unroll
    for (int db = 0; db < 2; db++) {
#pragma unroll
        for (int g = 0; g < 4; g++) {
            ushort4 stv;
            stv.x = f2b(oacc[db][g * 4 + 0] * inv);
            stv.y = f2b(oacc[db][g * 4 + 1] * inv);
            stv.z = f2b(oacc[db][g * 4 + 2] * inv);
            stv.w = f2b(oacc[db][g * 4 + 3] * inv);
            int col = h * 64 + db * 32 + g * 8 + hi * 4;
            *(ushort4*)&attn_out[(size_t)qrow * 1024 + col] = stv;
        }
    }
}

extern "C" void kernel_launch(void* const* d_in, const int* in_sizes, int n_in,
                              void* d_out, int out_size, void* d_ws, size_t ws_size,
                              hipStream_t stream) {
    (void)in_sizes; (void)n_in; (void)out_size; (void)ws_size;
    const float* x    = (const float*)d_in[0];
    const float* g    = (const float*)d_in[1];
    const float* be   = (const float*)d_in[2];
    const float* Wqkv = (const float*)d_in[3];
    const float* Wout = (const float*)d_in[4];
    const float* bout = (const float*)d_in[5];
    float* out = (float*)d_out;   // reference output dtype is fp32
    char* ws = (char*)d_ws;

    U16* xn   = (U16*)(ws);                          // 8 MB, reused as aout
    U16* qkv  = (U16*)(ws + (size_t)(8u  << 20));    // 24 MB (V third unused)
    U16* WqT  = (U16*)(ws + (size_t)(32u << 20));    // 6 MB
    U16* WoT  = (U16*)(ws + (size_t)(38u << 20));    // 2 MB
    U16* vT   = (U16*)(ws + (size_t)(40u << 20));    // 8 MB: V transposed
    U16* aout = xn;  // xn dead after GEMM1

    prep_kernel<<<8192, 256, 0, stream>>>(x, g, be, xn, Wqkv, WqT, Wout, WoT);
    gemm_g1<<<256, 512, 0, stream>>>(xn, WqT, qkv, vT, 4096, 3072, 1024);
    attn_kernel<<<512, 256, 0, stream>>>(qkv, vT, aout);
    gemm_bt2<<<dim3(1024 / 128, 4096 / 64), 256, 0, stream>>>(aout, WoT, bout, out, 4096, 1024, 1024);
}

// Round 13
// 179.730 us; speedup vs baseline: 1.0262x; 1.0036x over previous
//
#include <hip/hip_runtime.h>

typedef unsigned short U16;
typedef __bf16 bf16x8 __attribute__((ext_vector_type(8)));
typedef float f32x4 __attribute__((ext_vector_type(4)));
typedef float f32x16 __attribute__((ext_vector_type(16)));
typedef U16 u16x8 __attribute__((ext_vector_type(8)));

__device__ inline float b2f(U16 u) {
    union { unsigned int i; float f; } v;
    v.i = ((unsigned int)u) << 16;
    return v.f;
}
__device__ inline U16 f2b(float f) {
    union { float f; unsigned int u; } v;
    v.f = f;
    unsigned int r = (v.u + 0x7fffu + ((v.u >> 16) & 1u)) >> 16;
    return (U16)r;
}

// pack two f32 -> two bf16 in one u32 (RNE, same as f2b)
__device__ inline unsigned cvt_pk(float lo, float hi) {
    unsigned d;
    asm("v_cvt_pk_bf16_f32 %0, %1, %2" : "=v"(d) : "v"(lo), "v"(hi));
    return d;
}
// swap: a[lanes 32-63] <-> b[lanes 0-31]
__device__ inline void plswap(unsigned &a, unsigned &b) {
    asm("v_permlane32_swap_b32 %0, %1" : "+v"(a), "+v"(b));
}

// async global->LDS, 16B per lane (LDS dest = wave-uniform base + lane*16)
__device__ inline void gld16(const void* g, void* l) {
    __builtin_amdgcn_global_load_lds(
        (const __attribute__((address_space(1))) void*)g,
        (__attribute__((address_space(3))) void*)l, 16, 0, 0);
}

// ------- prep: LN (blocks 0..4095) + two weight transposes, ONE launch -----
__global__ __launch_bounds__(256) void prep_kernel(const float* __restrict__ x,
                                                   const float* __restrict__ gamma,
                                                   const float* __restrict__ beta,
                                                   U16* __restrict__ xn,
                                                   const float* __restrict__ Wqkv,
                                                   U16* __restrict__ WqT,
                                                   const float* __restrict__ Wout,
                                                   U16* __restrict__ WoT) {
    int p = blockIdx.x;
    int t = threadIdx.x;
    if (p < 4096) {
        // ---- LayerNorm row p: fp32 -> bf16 ----
        int row = p;
        float4 raw = ((const float4*)(x + (size_t)row * 1024))[t];
        float v[4] = { raw.x, raw.y, raw.z, raw.w };
        float s = v[0] + v[1] + v[2] + v[3];
        float s2 = v[0] * v[0] + v[1] * v[1] + v[2] * v[2] + v[3] * v[3];
#pragma unroll
        for (int off = 32; off >= 1; off >>= 1) {
            s  += __shfl_xor(s,  off);
            s2 += __shfl_xor(s2, off);
        }
        __shared__ float red[8];
        if ((t & 63) == 0) { red[(t >> 6) * 2] = s; red[(t >> 6) * 2 + 1] = s2; }
        __syncthreads();
        float S  = red[0] + red[2] + red[4] + red[6];
        float S2 = red[1] + red[3] + red[5] + red[7];
        float mu = S * (1.0f / 1024.0f);
        float var = S2 * (1.0f / 1024.0f) - mu * mu;
        float rstd = rsqrtf(var + 1e-5f);
        float4 g4 = ((const float4*)gamma)[t];
        float4 b4 = ((const float4*)beta)[t];
        ushort4 o;
        o.x = f2b((v[0] - mu) * rstd * g4.x + b4.x);
        o.y = f2b((v[1] - mu) * rstd * g4.y + b4.y);
        o.z = f2b((v[2] - mu) * rstd * g4.z + b4.z);
        o.w = f2b((v[3] - mu) * rstd * g4.w + b4.w);
        ((ushort4*)(xn + (size_t)row * 1024))[t] = o;
        return;
    }
    // ---- transpose + f2b: out[c][r] = bf16(in[r][c]) ----
    p -= 4096;
    const float* in; U16* out; int C, tilesx;
    if (p < 3072) { in = Wqkv; out = WqT; C = 3072; tilesx = 96; }
    else { p -= 3072; in = Wout; out = WoT; C = 1024; tilesx = 32; }
    const int R = 1024;
    int c0 = (p % tilesx) * 32, r0 = (p / tilesx) * 32;
    int tx = t & 31, ty = t >> 5;   // 32 x 8
    __shared__ float tile[32][33];
#pragma unroll
    for (int i = 0; i < 32; i += 8)
        tile[ty + i][tx] = in[(size_t)(r0 + ty + i) * C + c0 + tx];
    __syncthreads();
#pragma unroll
    for (int i = 0; i < 32; i += 8)
        out[(size_t)(c0 + ty + i) * R + r0 + tx] = f2b(tile[tx][ty + i]);
}

// ------ GEMM1: 256x192 tile, BK=64, 8 waves, counted-vmcnt pipeline.
// r12-proven schedule (180.4us total): stA(t+1) at top with vmcnt(4),
// stB(t+1) mid-tile, no mid-tile barrier (P0/P1 read the same buffer).
//
// NEW this round: the vT epilogue previously wrote 8B/lane at a 4KB lane
// stride (dd = col&63 varies per lane) — 8 MB of V output as isolated 8B
// transactions. Now each wave transposes its 16x128 V sub-tile through a
// PRIVATE 4KB LDS region (aliases As, dead after the K-loop; the final
// ktile barrier guarantees all waves' LDS reads retired) and stores
// contiguous 256B segments along nn. Oct-XOR swizzle (oct^col) keeps both
// LDS sides <=2-way (free, m136). Wave-private -> no new barriers -> no
// hang path. Values bit-identical.
__global__ __launch_bounds__(512) void gemm_g1(const U16* __restrict__ A,
                                               const U16* __restrict__ Bt,
                                               U16* __restrict__ C,
                                               U16* __restrict__ vT,
                                               int M, int N, int K) {
    __shared__ __align__(16) U16 As[2][2][128 * 64];   // 64 KB
    __shared__ __align__(16) U16 Bs[2][192 * 64];      // 48 KB
    const int p = blockIdx.x;
    const int xcd = p & 7, sl = p >> 3;              // sl in 0..31
    const int by = xcd * 2 + (sl >> 4);
    const int bx = sl & 15;
    const int m0 = by * 256, n0 = bx * 192;
    const int t = threadIdx.x;
    const int wave = t >> 6, lane = t & 63, l15 = lane & 15, quad = lane >> 4;
    const int wm = wave >> 2, wn = wave & 3;

    f32x4 acc[8][3];
#pragma unroll
    for (int i = 0; i < 8; i++)
#pragma unroll
        for (int j = 0; j < 3; j++)
            acc[i][j] = (f32x4){0.f, 0.f, 0.f, 0.f};

    // A staging: 2048 chunks per 256-row tile (2 halves x 1024), 4/thread
    const int c0 = t, c1 = 512 + t;
    const int sr0 = c0 >> 3, so0 = (c0 & 7) ^ (sr0 & 7);
    const int sr1 = c1 >> 3, so1 = (c1 & 7) ^ (sr1 & 7);
    const U16* Ag0 = A + (size_t)(m0 + sr0) * K + so0 * 8;
    const U16* Ag1 = A + (size_t)(m0 + sr1) * K + so1 * 8;
    const size_t hstep = (size_t)128 * K;           // +128 rows

    // B staging: 1536 chunks per 192-row tile, 3/thread
    const int cb2 = 1024 + t;
    const int sb2 = cb2 >> 3, ob2 = (cb2 & 7) ^ (sb2 & 7);
    const U16* Bg0 = Bt + (size_t)(n0 + sr0) * K + so0 * 8;   // chunk t
    const U16* Bg1 = Bt + (size_t)(n0 + sr1) * K + so1 * 8;   // chunk 512+t
    const U16* Bg2 = Bt + (size_t)(n0 + sb2) * K + ob2 * 8;   // chunk 1024+t

    auto stA = [&](int kt, U16* d0, U16* d1) {      // 4 loads
        gld16(Ag0 + kt * 64, d0 + c0 * 8);
        gld16(Ag1 + kt * 64, d0 + c1 * 8);
        gld16(Ag0 + hstep + kt * 64, d1 + c0 * 8);
        gld16(Ag1 + hstep + kt * 64, d1 + c1 * 8);
    };
    auto stB = [&](int kt, U16* d) {                // 3 loads
        gld16(Bg0 + kt * 64, d + c0 * 8);
        gld16(Bg1 + kt * 64, d + c1 * 8);
        gld16(Bg2 + kt * 64, d + cb2 * 8);
    };

    // frag-read offsets (elements): k 0..31 -> oct quad, k 32..63 -> 4+quad
    const int slot0 = quad ^ (l15 & 7);
    const int slot1 = (4 + quad) ^ (l15 & 7);
    const int aoff0 = l15 * 64 + slot0 * 8, aoff1 = l15 * 64 + slot1 * 8;
    const int boff0 = wn * 48 * 64 + aoff0, boff1 = wn * 48 * 64 + aoff1;
    const int nk = K >> 6;                          // 16

    auto ktile = [&](const U16* Ac0, const U16* Ac1, const U16* Bc,
                     U16* An0, U16* An1, U16* Bn, int kt) {
        const bool nx = (kt + 1) < nk;
        if (nx) {
            stA(kt + 1, An0, An1);
            asm volatile("s_waitcnt vmcnt(4)" ::: "memory");
        } else {
            asm volatile("s_waitcnt vmcnt(0)" ::: "memory");
        }
        __builtin_amdgcn_s_barrier();
        asm volatile("" ::: "memory");
        const U16* Ah = wm ? Ac1 : Ac0;
        bf16x8 bfr[3][2], af[4][2];
#pragma unroll
        for (int j = 0; j < 3; j++) {
            bfr[j][0] = *(const bf16x8*)&Bc[j * 16 * 64 + boff0];
            bfr[j][1] = *(const bf16x8*)&Bc[j * 16 * 64 + boff1];
        }
#pragma unroll
        for (int i = 0; i < 4; i++) {
            af[i][0] = *(const bf16x8*)&Ah[i * 16 * 64 + aoff0];
            af[i][1] = *(const bf16x8*)&Ah[i * 16 * 64 + aoff1];
        }
        if (nx) stB(kt + 1, Bn);
        __builtin_amdgcn_s_setprio(1);
#pragma unroll
        for (int i = 0; i < 4; i++)
#pragma unroll
            for (int j = 0; j < 3; j++) {
                acc[i][j] = __builtin_amdgcn_mfma_f32_16x16x32_bf16(af[i][0], bfr[j][0], acc[i][j], 0, 0, 0);
                acc[i][j] = __builtin_amdgcn_mfma_f32_16x16x32_bf16(af[i][1], bfr[j][1], acc[i][j], 0, 0, 0);
            }
        __builtin_amdgcn_s_setprio(0);
        // (mid-tile barrier removed: P1 reads the same buffer as P0)
#pragma unroll
        for (int i = 0; i < 4; i++) {
            af[i][0] = *(const bf16x8*)&Ah[(4 + i) * 16 * 64 + aoff0];
            af[i][1] = *(const bf16x8*)&Ah[(4 + i) * 16 * 64 + aoff1];
        }
        __builtin_amdgcn_s_setprio(1);
#pragma unroll
        for (int i = 0; i < 4; i++)
#pragma unroll
            for (int j = 0; j < 3; j++) {
                acc[4 + i][j] = __builtin_amdgcn_mfma_f32_16x16x32_bf16(af[i][0], bfr[j][0], acc[4 + i][j], 0, 0, 0);
                acc[4 + i][j] = __builtin_amdgcn_mfma_f32_16x16x32_bf16(af[i][1], bfr[j][1], acc[4 + i][j], 0, 0, 0);
            }
        __builtin_amdgcn_s_setprio(0);
        asm volatile("" ::: "memory");
        __builtin_amdgcn_s_barrier();
        asm volatile("" ::: "memory");
    };

    // prologue: tile 0 -> buf 0, full drain once
    stA(0, &As[0][0][0], &As[0][1][0]);
    stB(0, &Bs[0][0]);
    asm volatile("s_waitcnt vmcnt(0)" ::: "memory");
    __builtin_amdgcn_s_barrier();
    asm volatile("" ::: "memory");

    for (int kt = 0; kt < nk; kt += 2) {
        ktile(&As[0][0][0], &As[0][1][0], &Bs[0][0],
              &As[1][0][0], &As[1][1][0], &Bs[1][0], kt);
        ktile(&As[1][0][0], &As[1][1][0], &Bs[1][0],
              &As[0][0][0], &As[0][1][0], &Bs[0][0], kt + 1);
    }

    // epilogue: per-j V-vs-C branch (j-blocks are 16-aligned; 2048 % 16 == 0)
    // V path: wave-private LDS transpose (4 KB @ As + wave*2048 elems) ->
    // coalesced 256B-per-16-lane vT stores. Logical (col c, oct o, off w)
    // stored at phys elem c*128 + ((o^c)&15)*8 + w (oct-XOR: <=2-way banks).
    U16* tb = &As[0][0][0] + wave * 2048;
    const int bbw = (m0 + wm * 128) >> 11;
    const int nnb = (m0 + wm * 128) & 2047;
#pragma unroll
    for (int j = 0; j < 3; j++) {
        int cb = n0 + wn * 48 + j * 16;
        if (vT && cb >= 2048) {
            asm volatile("s_waitcnt lgkmcnt(0)" ::: "memory");  // prior j's reads done
#pragma unroll
            for (int i = 0; i < 8; i++) {
                int oct = i * 2 + (quad >> 1);
                int phys = l15 * 128 + (((oct ^ l15) & 15) << 3) + (quad & 1) * 4;
                ushort4 st;
                st.x = f2b(acc[i][j][0]); st.y = f2b(acc[i][j][1]);
                st.z = f2b(acc[i][j][2]); st.w = f2b(acc[i][j][3]);
                *(ushort4*)&tb[phys] = st;
            }
            asm volatile("s_waitcnt lgkmcnt(0)" ::: "memory");
            int kp = lane & 15;                      // row-oct (8 rows)
#pragma unroll
            for (int pass = 0; pass < 4; pass++) {
                int cc = (lane >> 4) + pass * 4;     // local col 0..15
                int colg = cb + cc - 2048;
                int hh = colg >> 6, dd = colg & 63;
                u16x8 v = *(const u16x8*)&tb[cc * 128 + (((kp ^ cc) & 15) << 3)];
                *(u16x8*)&vT[((((size_t)bbw * 16) + hh) * 64 + dd) * 2048 + nnb + kp * 8] = v;
            }
        } else {
#pragma unroll
            for (int i = 0; i < 8; i++) {
                int col = cb + l15;
                int row0 = m0 + wm * 128 + i * 16 + quad * 4;
#pragma unroll
                for (int r = 0; r < 4; r++)
                    C[(size_t)(row0 + r) * N + col] = f2b(acc[i][j][r]);
            }
        }
    }
}

// ------ GEMM2: 64x128 tile, BK=64, counted-vmcnt pipeline (r9 schedule:
// stAf at top with vmcnt(2), stBf mid-tile — proven).
__global__ __launch_bounds__(256) void gemm_bt2(const U16* __restrict__ A,
                                                const U16* __restrict__ Bt,
                                                const float* __restrict__ bias,
                                                float* __restrict__ C,
                                                int M, int N, int K) {
    __shared__ __align__(16) U16 As[2][64 * 64];
    __shared__ __align__(16) U16 Bs[2][128 * 64];
    const int m0 = blockIdx.y * 64, n0 = blockIdx.x * 128;
    const int t = threadIdx.x;
    const int wave = t >> 6, lane = t & 63, l15 = lane & 15, quad = lane >> 4;
    const int wm = (wave >> 1) * 32, wn = (wave & 1) * 64;

    f32x4 acc[2][4];
#pragma unroll
    for (int i = 0; i < 2; i++)
#pragma unroll
        for (int j = 0; j < 4; j++)
            acc[i][j] = (f32x4){0.f, 0.f, 0.f, 0.f};

    const int cA0 = t, cA1 = 256 + t;
    const int srA0 = cA0 >> 3, soA0 = (cA0 & 7) ^ (srA0 & 7);
    const int srA1 = cA1 >> 3, soA1 = (cA1 & 7) ^ (srA1 & 7);
    const U16* AgA0 = A + (size_t)(m0 + srA0) * K + soA0 * 8;
    const U16* AgA1 = A + (size_t)(m0 + srA1) * K + soA1 * 8;
    const int cB0 = t, cB1 = 256 + t, cB2 = 512 + t, cB3 = 768 + t;
    const int srB0 = cB0 >> 3, soB0 = (cB0 & 7) ^ (srB0 & 7);
    const int srB1 = cB1 >> 3, soB1 = (cB1 & 7) ^ (srB1 & 7);
    const int srB2 = cB2 >> 3, soB2 = (cB2 & 7) ^ (srB2 & 7);
    const int srB3 = cB3 >> 3, soB3 = (cB3 & 7) ^ (srB3 & 7);
    const U16* BgB0 = Bt + (size_t)(n0 + srB0) * K + soB0 * 8;
    const U16* BgB1 = Bt + (size_t)(n0 + srB1) * K + soB1 * 8;
    const U16* BgB2 = Bt + (size_t)(n0 + srB2) * K + soB2 * 8;
    const U16* BgB3 = Bt + (size_t)(n0 + srB3) * K + soB3 * 8;

    auto stAf = [&](int kt, U16* d) {               // 2 loads
        gld16(AgA0 + kt * 64, d + cA0 * 8);
        gld16(AgA1 + kt * 64, d + cA1 * 8);
    };
    auto stBf = [&](int kt, U16* d) {               // 4 loads
        gld16(BgB0 + kt * 64, d + cB0 * 8);
        gld16(BgB1 + kt * 64, d + cB1 * 8);
        gld16(BgB2 + kt * 64, d + cB2 * 8);
        gld16(BgB3 + kt * 64, d + cB3 * 8);
    };

    const int as0 = (quad ^ (l15 & 7)) * 8;
    const int as1 = ((4 + quad) ^ (l15 & 7)) * 8;
    const int nk = K >> 6;                          // 16

    auto ktile = [&](const U16* Ac, const U16* Bc, U16* An, U16* Bn, int kt) {
        const bool nx = (kt + 1) < nk;
        if (nx) {
            stAf(kt + 1, An);
            asm volatile("s_waitcnt vmcnt(2)" ::: "memory");
        } else {
            asm volatile("s_waitcnt vmcnt(0)" ::: "memory");
        }
        __builtin_amdgcn_s_barrier();
        asm volatile("" ::: "memory");
        bf16x8 af[2][2], bfr[4][2];
#pragma unroll
        for (int i = 0; i < 2; i++) {
            af[i][0] = *(const bf16x8*)&Ac[(wm + i * 16 + l15) * 64 + as0];
            af[i][1] = *(const bf16x8*)&Ac[(wm + i * 16 + l15) * 64 + as1];
        }
#pragma unroll
        for (int j = 0; j < 4; j++) {
            bfr[j][0] = *(const bf16x8*)&Bc[(wn + j * 16 + l15) * 64 + as0];
            bfr[j][1] = *(const bf16x8*)&Bc[(wn + j * 16 + l15) * 64 + as1];
        }
        if (nx) stBf(kt + 1, Bn);
        __builtin_amdgcn_s_setprio(1);
#pragma unroll
        for (int i = 0; i < 2; i++)
#pragma unroll
            for (int j = 0; j < 4; j++) {
                acc[i][j] = __builtin_amdgcn_mfma_f32_16x16x32_bf16(af[i][0], bfr[j][0], acc[i][j], 0, 0, 0);
                acc[i][j] = __builtin_amdgcn_mfma_f32_16x16x32_bf16(af[i][1], bfr[j][1], acc[i][j], 0, 0, 0);
            }
        __builtin_amdgcn_s_setprio(0);
        asm volatile("" ::: "memory");
        __builtin_amdgcn_s_barrier();
        asm volatile("" ::: "memory");
    };

    stAf(0, &As[0][0]);
    stBf(0, &Bs[0][0]);
    asm volatile("s_waitcnt vmcnt(0)" ::: "memory");
    __builtin_amdgcn_s_barrier();
    asm volatile("" ::: "memory");

    for (int kt = 0; kt < nk; kt += 2) {
        ktile(&As[0][0], &Bs[0][0], &As[1][0], &Bs[1][0], kt);
        ktile(&As[1][0], &Bs[1][0], &As[0][0], &Bs[0][0], kt + 1);
    }

#pragma unroll
    for (int i = 0; i < 2; i++) {
#pragma unroll
        for (int j = 0; j < 4; j++) {
            int col = n0 + wn + j * 16 + l15;
            float bv = bias[col];
#pragma unroll
            for (int r = 0; r < 4; r++) {
                int row = m0 + wm + i * 16 + quad * 4 + r;
                C[(size_t)row * N + col] = acc[i][j][r] + bv;
            }
        }
    }
}

// ---- MFMA flash attention, in-register softmax (r7-proven 54us, parked) ---
__global__ __launch_bounds__(256) void attn_kernel(const U16* __restrict__ qkv,
                                                   const U16* __restrict__ vT,
                                                   U16* __restrict__ attn_out) {
    const int p = blockIdx.x;                    // 0..511
    const int xcd = p & 7;
    const int slot = p >> 3;                     // 0..63 within XCD
    const int bh = ((slot & 3) << 3) | xcd;      // bh & 7 == XCD id
    const int qt = slot >> 2;                    // 0..15, 128 q-rows per block
    const int b = bh >> 4, h = bh & 15;
    const int t = threadIdx.x;
    const int wave = t >> 6, lane = t & 63;
    const int l31 = lane & 31, hi = lane >> 5;
    const float sc2 = 0.125f * 1.44269504089f;  // scale * log2(e)

    __shared__ __align__(16) U16 Kt[2][64 * 64];    // [key][d-swizzled]
    __shared__ __align__(16) U16 Vt[2][64 * 64];    // [d][key-swizzled]

    const size_t base = (size_t)(b * 2048) * 3072;
    const U16* vTbh = vT + ((size_t)(b * 16 + h) * 64) * 2048;

    // Q fragments, pre-scaled by sc2 (softmax = exp2(S) with no per-iter mul)
    bf16x8 qf[4];
    {
        int qrow = qt * 128 + wave * 32 + l31;
        const U16* qp = qkv + base + (size_t)qrow * 3072 + h * 64 + hi * 8;
#pragma unroll
        for (int s = 0; s < 4; s++) {
            union { bf16x8 v; U16 u[8]; } a;
            a.v = *(const bf16x8*)&qp[s * 16];
#pragma unroll
            for (int e = 0; e < 8; e++) a.u[e] = f2b(b2f(a.u[e]) * sc2);
            qf[s] = a.v;
        }
    }

    float l4[4] = { 0.f, 0.f, 0.f, 0.f };
    f32x16 oacc[2];  // O^T[d][q]: d = db*32 + (reg&3)+8*(reg>>2)+4*hi, q=l31
#pragma unroll
    for (int db = 0; db < 2; db++)
#pragma unroll
        for (int r = 0; r < 16; r++)
            oacc[db][r] = 0.0f;

    const int c0 = t, c1 = 256 + t;
    const int row0 = c0 >> 3, oct0 = (c0 & 7) ^ (row0 & 7);
    const int row1 = c1 >> 3, oct1 = (c1 & 7) ^ (row1 & 7);

    gld16(&qkv[base + (size_t)row0 * 3072 + 1024 + h * 64 + oct0 * 8], &Kt[0][c0 * 8]);
    gld16(&qkv[base + (size_t)row1 * 3072 + 1024 + h * 64 + oct1 * 8], &Kt[0][c1 * 8]);
    gld16(&vTbh[(size_t)row0 * 2048 + oct0 * 8], &Vt[0][c0 * 8]);
    gld16(&vTbh[(size_t)row1 * 2048 + oct1 * 8], &Vt[0][c1 * 8]);
    __syncthreads();

    auto step = [&](const U16* KtC, const U16* VtC, U16* KtN, U16* VtN, int nt) {
        gld16(&qkv[base + (size_t)(nt * 64 + row0) * 3072 + 1024 + h * 64 + oct0 * 8], &KtN[c0 * 8]);
        gld16(&qkv[base + (size_t)(nt * 64 + row1) * 3072 + 1024 + h * 64 + oct1 * 8], &KtN[c1 * 8]);
        gld16(&vTbh[(size_t)row0 * 2048 + nt * 64 + oct0 * 8], &VtN[c0 * 8]);
        gld16(&vTbh[(size_t)row1 * 2048 + nt * 64 + oct1 * 8], &VtN[c1 * 8]);
#pragma unroll
        for (int kb = 0; kb < 2; kb++) {
            bf16x8 kf[4];
#pragma unroll
            for (int s = 0; s < 4; s++)
                kf[s] = *(const bf16x8*)&KtC[(kb * 32 + l31) * 64 +
                                             (((s * 2 + hi) ^ (l31 & 7)) * 8)];
            bf16x8 vfr[2][2];
#pragma unroll
            for (int db = 0; db < 2; db++)
#pragma unroll
                for (int s = 0; s < 2; s++)
                    vfr[db][s] = *(const bf16x8*)&VtC[(db * 32 + l31) * 64 +
                                                      (((kb * 4 + s * 2 + hi) ^ (l31 & 7)) * 8)];

            f32x16 st = {0.f, 0.f, 0.f, 0.f, 0.f, 0.f, 0.f, 0.f,
                         0.f, 0.f, 0.f, 0.f, 0.f, 0.f, 0.f, 0.f};
            __builtin_amdgcn_s_setprio(1);
#pragma unroll
            for (int s = 0; s < 4; s++)
                st = __builtin_amdgcn_mfma_f32_32x32x16_bf16(kf[s], qf[s], st, 0, 0, 0);
            __builtin_amdgcn_s_setprio(0);

            float pe[16];
#pragma unroll
            for (int r = 0; r < 16; r++) {
                pe[r] = __builtin_amdgcn_exp2f(st[r]);
                l4[r & 3] += pe[r];
            }

#pragma unroll
            for (int s = 0; s < 2; s++) {
                unsigned p01 = cvt_pk(pe[s * 8 + 0], pe[s * 8 + 1]);
                unsigned p23 = cvt_pk(pe[s * 8 + 2], pe[s * 8 + 3]);
                unsigned p45 = cvt_pk(pe[s * 8 + 4], pe[s * 8 + 5]);
                unsigned p67 = cvt_pk(pe[s * 8 + 6], pe[s * 8 + 7]);
                plswap(p01, p45);
                plswap(p23, p67);
                union { unsigned u[4]; bf16x8 v; } pw;
                pw.u[0] = p01; pw.u[1] = p23; pw.u[2] = p45; pw.u[3] = p67;
                __builtin_amdgcn_s_setprio(1);
#pragma unroll
                for (int db = 0; db < 2; db++)
                    oacc[db] = __builtin_amdgcn_mfma_f32_32x32x16_bf16(
                        vfr[db][s], pw.v, oacc[db], 0, 0, 0);
                __builtin_amdgcn_s_setprio(0);
            }
        }
        __syncthreads();
    };

    for (int kt2 = 0; kt2 < 16; kt2++) {
        step(&Kt[0][0], &Vt[0][0], &Kt[1][0], &Vt[1][0], 2 * kt2 + 1);
        step(&Kt[1][0], &Vt[1][0], &Kt[0][0], &Vt[0][0], (2 * kt2 + 2) & 31);
    }

    float l_acc = (l4[0] + l4[1]) + (l4[2] + l4[3]);
    float lt = l_acc + __shfl_xor(l_acc, 32);
    float inv = 1.0f / lt;
    int qrow = b * 2048 + qt * 128 + wave * 32 + l31;
#pragma unroll
    for (int db = 0; db < 2; db++) {
#pragma unroll
        for (int g = 0; g < 4; g++) {
            ushort4 stv;
            stv.x = f2b(oacc[db][g * 4 + 0] * inv);
            stv.y = f2b(oacc[db][g * 4 + 1] * inv);
            stv.z = f2b(oacc[db][g * 4 + 2] * inv);
            stv.w = f2b(oacc[db][g * 4 + 3] * inv);
            int col = h * 64 + db * 32 + g * 8 + hi * 4;
            *(ushort4*)&attn_out[(size_t)qrow * 1024 + col] = stv;
        }
    }
}

extern "C" void kernel_launch(void* const* d_in, const int* in_sizes, int n_in,
                              void* d_out, int out_size, void* d_ws, size_t ws_size,
                              hipStream_t stream) {
    (void)in_sizes; (void)n_in; (void)out_size; (void)ws_size;
    const float* x    = (const float*)d_in[0];
    const float* g    = (const float*)d_in[1];
    const float* be   = (const float*)d_in[2];
    const float* Wqkv = (const float*)d_in[3];
    const float* Wout = (const float*)d_in[4];
    const float* bout = (const float*)d_in[5];
    float* out = (float*)d_out;   // reference output dtype is fp32
    char* ws = (char*)d_ws;

    U16* xn   = (U16*)(ws);                          // 8 MB, reused as aout
    U16* qkv  = (U16*)(ws + (size_t)(8u  << 20));    // 24 MB (V third unused)
    U16* WqT  = (U16*)(ws + (size_t)(32u << 20));    // 6 MB
    U16* WoT  = (U16*)(ws + (size_t)(38u << 20));    // 2 MB
    U16* vT   = (U16*)(ws + (size_t)(40u << 20));    // 8 MB: V transposed
    U16* aout = xn;  // xn dead after GEMM1

    prep_kernel<<<8192, 256, 0, stream>>>(x, g, be, xn, Wqkv, WqT, Wout, WoT);
    gemm_g1<<<256, 512, 0, stream>>>(xn, WqT, qkv, vT, 4096, 3072, 1024);
    attn_kernel<<<512, 256, 0, stream>>>(qkv, vT, aout);
    gemm_bt2<<<dim3(1024 / 128, 4096 / 64), 256, 0, stream>>>(aout, WoT, bout, out, 4096, 1024, 1024);
}